// Round 1
// baseline (490.857 us; speedup 1.0000x reference)
//
#include <hip/hip_runtime.h>

#define NN 262144   // nodes
#define DD 256      // channels
#define BB 1024     // graphs
#define GEPS 1e-5f

// ws layout (floats): [0,BB)=sum, [BB,2BB)=sumsq, [2BB,3BB)=count,
//                     [3BB,4BB)=mean, [4BB,5BB)=inv_std

__global__ void k_zero(float* __restrict__ sums) {
    int i = blockIdx.x * blockDim.x + threadIdx.x;
    if (i < 3 * BB) sums[i] = 0.0f;
}

__global__ __launch_bounds__(256) void k_accum(const float4* __restrict__ x,
                                               const int* __restrict__ batch,
                                               float* __restrict__ sums) {
    const int wid  = (blockIdx.x * blockDim.x + threadIdx.x) >> 6;
    const int lane = threadIdx.x & 63;
    const int nw   = (gridDim.x * blockDim.x) >> 6;
    for (int row = wid; row < NN; row += nw) {
        float4 v = x[row * 64 + lane];      // 64 lanes * 4 floats = 256 = D
        float s = v.x + v.y + v.z + v.w;
        float q = v.x * v.x + v.y * v.y + v.z * v.z + v.w * v.w;
        #pragma unroll
        for (int off = 32; off; off >>= 1) {
            s += __shfl_down(s, off, 64);
            q += __shfl_down(q, off, 64);
        }
        if (lane == 0) {
            int b = batch[row];
            atomicAdd(&sums[b], s);
            atomicAdd(&sums[BB + b], q);
            atomicAdd(&sums[2 * BB + b], 1.0f);
        }
    }
}

__global__ void k_stats(const float* __restrict__ sums, float* __restrict__ stats) {
    int b = blockIdx.x * blockDim.x + threadIdx.x;
    if (b < BB) {
        float cnt  = sums[2 * BB + b];
        float norm = fmaxf(cnt, 1.0f) * (float)DD;
        float mean = sums[b] / norm;
        float var  = fmaxf(sums[BB + b] / norm - mean * mean, 0.0f);
        stats[b]      = mean;
        stats[BB + b] = 1.0f / (sqrtf(var) + GEPS);
    }
}

__global__ __launch_bounds__(256) void k_norm(const float4* __restrict__ x,
                                              const int* __restrict__ batch,
                                              const float* __restrict__ stats,
                                              const float4* __restrict__ w,
                                              const float4* __restrict__ bi,
                                              float4* __restrict__ out) {
    const int wid  = (blockIdx.x * blockDim.x + threadIdx.x) >> 6;
    const int lane = threadIdx.x & 63;
    const int nw   = (gridDim.x * blockDim.x) >> 6;
    const float4 wv = w[lane];
    const float4 bv = bi[lane];
    for (int row = wid; row < NN; row += nw) {
        int b = batch[row];
        float mean = stats[b];
        float inv  = stats[BB + b];
        float4 v = x[row * 64 + lane];
        float4 o;
        o.x = (v.x - mean) * inv * wv.x + bv.x;
        o.y = (v.y - mean) * inv * wv.y + bv.y;
        o.z = (v.z - mean) * inv * wv.z + bv.z;
        o.w = (v.w - mean) * inv * wv.w + bv.w;
        out[row * 64 + lane] = o;
    }
}

extern "C" void kernel_launch(void* const* d_in, const int* in_sizes, int n_in,
                              void* d_out, int out_size, void* d_ws, size_t ws_size,
                              hipStream_t stream) {
    const float4* x     = (const float4*)d_in[0];
    const int*    batch = (const int*)d_in[1];
    const float4* w     = (const float4*)d_in[2];
    const float4* bi    = (const float4*)d_in[3];
    float4*       out   = (float4*)d_out;

    float* sums  = (float*)d_ws;           // 3*BB floats
    float* stats = sums + 3 * BB;          // 2*BB floats

    k_zero<<<(3 * BB + 255) / 256, 256, 0, stream>>>(sums);
    k_accum<<<2048, 256, 0, stream>>>(x, batch, sums);
    k_stats<<<BB / 256, 256, 0, stream>>>(sums, stats);
    k_norm<<<2048, 256, 0, stream>>>(x, batch, stats, w, bi, out);
}

// Round 2
// 159.594 us; speedup vs baseline: 3.0757x; 3.0757x over previous
//
#include <hip/hip_runtime.h>

#define NN 262144   // nodes
#define DD 256      // channels
#define BB 1024     // graphs
#define GEPS 1e-5f
#define ROWS_PER_WAVE 32
#define NWAVES (NN / ROWS_PER_WAVE)   // 8192 waves
#define NBLOCKS (NWAVES / 4)          // 256 threads = 4 waves per block

// ws layout (floats): [0,BB)=sum, [BB,2BB)=sumsq, [2BB,3BB)=count,
//                     [3BB,4BB)=mean, [4BB,5BB)=inv_std

__global__ void k_zero(float* __restrict__ sums) {
    int i = blockIdx.x * blockDim.x + threadIdx.x;
    if (i < 3 * BB) sums[i] = 0.0f;
}

__device__ __forceinline__ void flush_seg(float* __restrict__ sums, int b,
                                          float s, float q, int runlen, int lane) {
    #pragma unroll
    for (int off = 32; off; off >>= 1) {
        s += __shfl_down(s, off, 64);
        q += __shfl_down(q, off, 64);
    }
    if (lane == 0) {
        atomicAdd(&sums[b], s);
        atomicAdd(&sums[BB + b], q);
        atomicAdd(&sums[2 * BB + b], (float)runlen);
    }
}

__global__ __launch_bounds__(256) void k_accum(const float4* __restrict__ x,
                                               const int* __restrict__ batch,
                                               float* __restrict__ sums) {
    const int wid  = (blockIdx.x * blockDim.x + threadIdx.x) >> 6;
    const int lane = threadIdx.x & 63;
    const int r0   = wid * ROWS_PER_WAVE;   // contiguous chunk (batch is sorted)

    int   cur = batch[r0];
    float s = 0.0f, q = 0.0f;
    int   runlen = 0;

    for (int i = 0; i < ROWS_PER_WAVE; ++i) {
        const int row = r0 + i;
        const int b = batch[row];            // wave-uniform; 1 line per wave
        if (b != cur) {                      // uniform branch (sorted input)
            flush_seg(sums, cur, s, q, runlen, lane);
            s = 0.0f; q = 0.0f; runlen = 0; cur = b;
        }
        float4 v = x[row * 64 + lane];       // 64 lanes * 16B = full row
        s += v.x + v.y + v.z + v.w;
        q += v.x * v.x + v.y * v.y + v.z * v.z + v.w * v.w;
        ++runlen;
    }
    flush_seg(sums, cur, s, q, runlen, lane);
}

__global__ void k_stats(const float* __restrict__ sums, float* __restrict__ stats) {
    int b = blockIdx.x * blockDim.x + threadIdx.x;
    if (b < BB) {
        float cnt  = sums[2 * BB + b];
        float norm = fmaxf(cnt, 1.0f) * (float)DD;
        float mean = sums[b] / norm;
        float var  = fmaxf(sums[BB + b] / norm - mean * mean, 0.0f);
        stats[b]      = mean;
        stats[BB + b] = 1.0f / (sqrtf(var) + GEPS);
    }
}

__global__ __launch_bounds__(256) void k_norm(const float4* __restrict__ x,
                                              const int* __restrict__ batch,
                                              const float* __restrict__ stats,
                                              const float4* __restrict__ w,
                                              const float4* __restrict__ bi,
                                              float4* __restrict__ out) {
    const int wid  = (blockIdx.x * blockDim.x + threadIdx.x) >> 6;
    const int lane = threadIdx.x & 63;
    const int nw   = (gridDim.x * blockDim.x) >> 6;
    const float4 wv = w[lane];
    const float4 bv = bi[lane];
    for (int row = wid; row < NN; row += nw) {
        int b = batch[row];
        float mean = stats[b];
        float inv  = stats[BB + b];
        float4 v = x[row * 64 + lane];
        float4 o;
        o.x = (v.x - mean) * inv * wv.x + bv.x;
        o.y = (v.y - mean) * inv * wv.y + bv.y;
        o.z = (v.z - mean) * inv * wv.z + bv.z;
        o.w = (v.w - mean) * inv * wv.w + bv.w;
        out[row * 64 + lane] = o;
    }
}

extern "C" void kernel_launch(void* const* d_in, const int* in_sizes, int n_in,
                              void* d_out, int out_size, void* d_ws, size_t ws_size,
                              hipStream_t stream) {
    const float4* x     = (const float4*)d_in[0];
    const int*    batch = (const int*)d_in[1];
    const float4* w     = (const float4*)d_in[2];
    const float4* bi    = (const float4*)d_in[3];
    float4*       out   = (float4*)d_out;

    float* sums  = (float*)d_ws;           // 3*BB floats
    float* stats = sums + 3 * BB;          // 2*BB floats

    k_zero<<<(3 * BB + 255) / 256, 256, 0, stream>>>(sums);
    k_accum<<<NBLOCKS, 256, 0, stream>>>(x, batch, sums);
    k_stats<<<BB / 256, 256, 0, stream>>>(sums, stats);
    k_norm<<<2048, 256, 0, stream>>>(x, batch, stats, w, bi, out);
}

// Round 5
// 127.448 us; speedup vs baseline: 3.8514x; 1.2522x over previous
//
#include <hip/hip_runtime.h>

#define NN 262144   // nodes
#define DD 256      // channels
#define BB 1024     // graphs
#define GEPS 1e-5f

typedef float floatx4 __attribute__((ext_vector_type(4)));

// One block (1024 threads = 16 waves) per graph. No workspace, no cross-kernel
// state: each block finds its own [s0,s1) in the sorted batch array via a
// two-phase parallel lower_bound, computes scalar mean/var over the segment,
// then normalizes, re-reading rows that are hot in L2/L3.
__global__ __launch_bounds__(1024) void k_main(const float4* __restrict__ x,
                                               const int* __restrict__ batch,
                                               const float4* __restrict__ w,
                                               const float4* __restrict__ bi,
                                               float4* __restrict__ out) {
    __shared__ int   s_coarse[2];
    __shared__ int   s_pos[2];     // written exactly once each (unique hit)
    __shared__ float red_s[16];
    __shared__ float red_q[16];
    __shared__ float bc[2];

    const int b    = blockIdx.x;
    const int tid  = threadIdx.x;
    const int wid  = tid >> 6;     // 0..15
    const int lane = tid & 63;

    // --- phase 1: coarse lower_bound at stride 256 (targets b and b+1) ---
    if (tid < 2) s_coarse[tid] = NN;
    __syncthreads();
    {
        const int idx = tid << 8;              // 0,256,...,NN-256
        const int v   = batch[idx];
        if (v >= b)     atomicMin(&s_coarse[0], idx);
        if (v >= b + 1) atomicMin(&s_coarse[1], idx);
    }
    __syncthreads();
    // --- phase 2: exact boundary within (coarse-256, coarse] ---
    {
        const int k = tid >> 8;                // 0..3
        const int t = tid & 255;
        if (k < 2) {
            const int tgt = b + k;
            const int cc  = s_coarse[k];
            const int i   = cc - 255 + t;      // covers cc-255 .. cc
            if (i >= 0) {
                const int vi  = (i < NN) ? batch[i] : 0x7fffffff;
                const int vim = (i > 0) ? batch[i - 1] : (-2147483647 - 1);
                if (vi >= tgt && vim < tgt) s_pos[k] = i;   // unique hit
            }
        }
    }
    __syncthreads();
    const int s0 = s_pos[0];
    const int s1 = s_pos[1];
    if (s1 <= s0) return;                      // empty graph (block-uniform)

    // --- pass 1: scalar sum / sumsq over the whole segment ---
    float s = 0.0f, q = 0.0f;
    for (int r = s0 + wid; r < s1; r += 16) {
        float4 v = x[r * 64 + lane];           // 64 lanes * 16B = one 1 KiB row
        s += v.x + v.y + v.z + v.w;
        q += v.x * v.x + v.y * v.y + v.z * v.z + v.w * v.w;
    }
    #pragma unroll
    for (int off = 32; off; off >>= 1) {
        s += __shfl_down(s, off, 64);
        q += __shfl_down(q, off, 64);
    }
    if (lane == 0) { red_s[wid] = s; red_q[wid] = q; }
    __syncthreads();
    if (tid == 0) {
        float ts = 0.0f, tq = 0.0f;
        #pragma unroll
        for (int i = 0; i < 16; ++i) { ts += red_s[i]; tq += red_q[i]; }
        const float norm = (float)(s1 - s0) * (float)DD;   // deg >= 1 here
        const float mean = ts / norm;
        const float var  = fmaxf(tq / norm - mean * mean, 0.0f);
        bc[0] = mean;
        bc[1] = 1.0f / (sqrtf(var) + GEPS);
    }
    __syncthreads();
    const float  mean = bc[0];
    const float  inv  = bc[1];
    const float4 wv   = w[lane];
    const float4 bv   = bi[lane];

    // --- pass 2: normalize; x re-read is L2/L3-hot; out bypasses cache ---
    for (int r = s0 + wid; r < s1; r += 16) {
        float4 v = x[r * 64 + lane];
        floatx4 o;
        o.x = (v.x - mean) * inv * wv.x + bv.x;
        o.y = (v.y - mean) * inv * wv.y + bv.y;
        o.z = (v.z - mean) * inv * wv.z + bv.z;
        o.w = (v.w - mean) * inv * wv.w + bv.w;
        __builtin_nontemporal_store(o, (floatx4*)&out[r * 64 + lane]);
    }
}

extern "C" void kernel_launch(void* const* d_in, const int* in_sizes, int n_in,
                              void* d_out, int out_size, void* d_ws, size_t ws_size,
                              hipStream_t stream) {
    const float4* x     = (const float4*)d_in[0];
    const int*    batch = (const int*)d_in[1];
    const float4* w     = (const float4*)d_in[2];
    const float4* bi    = (const float4*)d_in[3];
    float4*       out   = (float4*)d_out;

    k_main<<<BB, 1024, 0, stream>>>(x, batch, w, bi, out);
}